// Round 6
// baseline (88.088 us; speedup 1.0000x reference)
//
#include <hip/hip_runtime.h>
#include <stdint.h>

constexpr int L_LEVELS = 16;
constexpr int T_SIZE   = 16384;
constexpr int N_PTS    = 262144;

typedef _Float16 h2 __attribute__((ext_vector_type(2)));
typedef _Float16 h4 __attribute__((ext_vector_type(4)));
typedef _Float16 h8 __attribute__((ext_vector_type(8)));

// Byte-offset-scaled hash constants: prime*4 mod 2^32, mask (T-1)*4.
constexpr uint32_t P1_4 = 2654435761u * 4u;
constexpr uint32_t P2_4 = 805459861u * 4u;
constexpr uint32_t M4   = (T_SIZE - 1) * 4u;   // 65532

__device__ __forceinline__ h2 lerp2(h2 a, h2 b, h2 t) {
    return a + t * (b - a);                     // v_pk_sub + v_pk_fma
}

// ---------------------------------------------------------------------------
// Kernel C: one-time emb f32 (L,T,2) -> fp16 (L,T) h2 copy in d_ws tail.
// 131072 float4 -> h4. Staging in A then needs no cvt and half the L2 bytes.
// ---------------------------------------------------------------------------
__global__ __launch_bounds__(256) void cvt_emb(
    const float4* __restrict__ src, h4* __restrict__ dst)
{
    const int i = blockIdx.x * 256 + threadIdx.x;       // 0..131071
    const float4 v = src[i];
    h4 w = { (_Float16)v.x, (_Float16)v.y, (_Float16)v.z, (_Float16)v.w };
    dst[i] = w;
}

// ---------------------------------------------------------------------------
// Kernel A: block = (level-pair lp/lp+8, chunk of 8192 points), 1024 threads,
// grid = 256 -> exactly 1 block/CU, single staging round. Both level tables
// in LDS as fp16 (128 KB). x read ONCE per 2 levels. Gray-code XOR corner
// addressing, packed-fp16 lerp tree, 2x dwordx4 ws stores per level.
// ---------------------------------------------------------------------------
__global__ __launch_bounds__(1024, 4) void hash_encode_pair(
    const float* __restrict__ x,
    const h2* __restrict__ emb16,
    h2* __restrict__ ws)
{
    __shared__ h2 tab[2][T_SIZE];               // 2 x 64 KB

    const int lp    = blockIdx.x & 7;           // levels lp and lp+8
    const int chunk = blockIdx.x >> 3;          // 0..31
    const int t     = threadIdx.x;              // 0..1023
    const int n0    = chunk * 8192 + t * 8;     // 8 consecutive points

    // ---- stage both tables: pure fp16 copy, 4 x 16 B per thread per table --
    {
        const float4* __restrict__ sA =
            reinterpret_cast<const float4*>(emb16 + (size_t)lp * T_SIZE);
        const float4* __restrict__ sB =
            reinterpret_cast<const float4*>(emb16 + (size_t)(lp + 8) * T_SIZE);
        float4* __restrict__ dA = reinterpret_cast<float4*>(tab[0]);
        float4* __restrict__ dB = reinterpret_cast<float4*>(tab[1]);
#pragma unroll
        for (int it = 0; it < 4; ++it) {
            dA[it * 1024 + t] = sA[it * 1024 + t];
            dB[it * 1024 + t] = sB[it * 1024 + t];
        }
    }

    // ---- prefetch this thread's 8 points (24 floats = 6 aligned float4) ----
    union { float4 q[6]; float f[24]; } xs;
    {
        const float4* __restrict__ xv =
            reinterpret_cast<const float4*>(x + (size_t)n0 * 3);
#pragma unroll
        for (int i = 0; i < 6; ++i) xs.q[i] = xv[i];
    }

    __syncthreads();

#pragma unroll 1
    for (int s = 0; s < 2; ++s) {               // two levels, x reused
        const int lv = lp + 8 * s;
        const float Nl = 16.0f * exp2f((float)lv * 0.3125f);
        const char* __restrict__ tb = reinterpret_cast<const char*>(tab[s]);

        union { h2 r[8]; float4 q[2]; } res;

#pragma unroll
        for (int p = 0; p < 8; ++p) {
            const float u0 = xs.f[3 * p + 0] * Nl;
            const float u1 = xs.f[3 * p + 1] * Nl;
            const float u2 = xs.f[3 * p + 2] * Nl;

            // u >= 0: df = u - floor(u); exact-integer case gives df=0 which
            // zeroes the (possibly wrong-slot) hi-corner lerp term.
            const float fl0 = floorf(u0), fl1 = floorf(u1), fl2 = floorf(u2);
            const float df0 = u0 - fl0, df1 = u1 - fl1, df2 = u2 - fl2;

            // Byte-offset hash products for the lo corner (prime*4, wrapping).
            const uint32_t q0 = ((uint32_t)(int32_t)fl0) << 2;   // prime 1
            const uint32_t q1 = ((uint32_t)(int32_t)fl1) * P1_4;
            const uint32_t q2 = ((uint32_t)(int32_t)fl2) * P2_4;
            const uint32_t d0 = (q0 ^ (q0 + 4u))   & M4;
            const uint32_t d1 = (q1 ^ (q1 + P1_4)) & M4;
            const uint32_t d2 = (q2 ^ (q2 + P2_4)) & M4;

            uint32_t off = (q0 ^ q1 ^ q2) & M4;  // corner 000 byte offset

            // Gray-code gather order: one XOR per subsequent corner address.
            constexpr int gray[8] = {0, 1, 3, 2, 6, 7, 5, 4};
            h2 f[8];
#pragma unroll
            for (int j = 0; j < 8; ++j) {
                f[gray[j]] = *reinterpret_cast<const h2*>(tb + off); // ds_read_b32
                if (j < 7) {
                    const int tog = gray[j] ^ gray[j + 1];           // 1,2 or 4
                    off ^= (tog == 4) ? d0 : (tog == 2) ? d1 : d2;
                }
            }

            // Packed-fp16 trilinear lerp tree.
            const _Float16 h0 = (_Float16)df0, h1 = (_Float16)df1,
                           hz = (_Float16)df2;
            const h2 t0 = {h0, h0}, t1 = {h1, h1}, t2 = {hz, hz};
            h2 e0 = lerp2(f[0], f[1], t2);
            h2 e1 = lerp2(f[2], f[3], t2);
            h2 e2 = lerp2(f[4], f[5], t2);
            h2 e3 = lerp2(f[6], f[7], t2);
            h2 g0 = lerp2(e0, e1, t1);
            h2 g1 = lerp2(e2, e3, t1);
            res.r[p] = lerp2(g0, g1, t0);
        }

        // ws[lv*N + n0 .. n0+7]: 32 B contiguous -> 2 dwordx4 stores.
        float4* ws4 = reinterpret_cast<float4*>(ws + (size_t)lv * N_PTS + n0);
        ws4[0] = res.q[0];
        ws4[1] = res.q[1];
    }
}

// ---------------------------------------------------------------------------
// Kernel B: transpose ws (L, N) half2 -> out (N, L) f32 via LDS tile.
// 512-point tiles: 8 B loads, b64 LDS writes, float4 stores (2 levels/store).
// Read-phase bank multiplicity <= 2-way (free).
// ---------------------------------------------------------------------------
__global__ __launch_bounds__(256) void transpose_lnf_nlf(
    const h2* __restrict__ ws,
    float4* __restrict__ out4)
{
    __shared__ h2 tile[L_LEVELS][514];          // stride 514: 8 B-aligned rows
    const int t    = threadIdx.x;
    const int base = blockIdx.x * 512;

#pragma unroll
    for (int l = 0; l < L_LEVELS; ++l) {
        const float2 v = *reinterpret_cast<const float2*>(
            ws + (size_t)l * N_PTS + base + 2 * t);      // 8 B/lane coalesced
        *reinterpret_cast<float2*>(&tile[l][2 * t]) = v; // ds_write_b64
    }
    __syncthreads();

#pragma unroll
    for (int i = 0; i < L_LEVELS; ++i) {
        const int flat = i * 256 + t;
        const int p  = flat >> 3;               // 0..511
        const int lp = flat & 7;                // level pair 2lp, 2lp+1
        h2 a = tile[2 * lp][p];
        h2 b = tile[2 * lp + 1][p];
        float4 o = { (float)a.x, (float)a.y, (float)b.x, (float)b.y };
        out4[(size_t)(base + p) * 8 + lp] = o;  // 16 B/lane, wave-contiguous
    }
}

// ---------------------------------------------------------------------------
// Fallback (ws too small): single-level blocks, f32->fp16 staging, strided
// direct f32 stores. Same math as round 5.
// ---------------------------------------------------------------------------
__global__ __launch_bounds__(512, 4) void hash_encode_direct(
    const float* __restrict__ x,
    const float* __restrict__ emb,
    float2* __restrict__ out)
{
    __shared__ h2 tab[T_SIZE];

    const int l     = blockIdx.x & (L_LEVELS - 1);
    const int chunk = blockIdx.x >> 4;
    const int t     = threadIdx.x;
    const int n0    = chunk * 4096 + t * 8;

    {
        const float4* __restrict__ src =
            reinterpret_cast<const float4*>(emb + (size_t)l * T_SIZE * 2);
        h8* __restrict__ d8 = reinterpret_cast<h8*>(tab);
#pragma unroll
        for (int it = 0; it < 8; ++it) {
            const int i = it * 512 + t;
            float4 a = src[2 * i];
            float4 b = src[2 * i + 1];
            h8 w = { (_Float16)a.x, (_Float16)a.y, (_Float16)a.z, (_Float16)a.w,
                     (_Float16)b.x, (_Float16)b.y, (_Float16)b.z, (_Float16)b.w };
            d8[i] = w;
        }
    }
    union { float4 q[6]; float f[24]; } xs;
    {
        const float4* __restrict__ xv =
            reinterpret_cast<const float4*>(x + (size_t)n0 * 3);
#pragma unroll
        for (int i = 0; i < 6; ++i) xs.q[i] = xv[i];
    }
    __syncthreads();

    const float Nl = 16.0f * exp2f((float)l * 0.3125f);
    const char* __restrict__ tb = reinterpret_cast<const char*>(tab);

#pragma unroll
    for (int p = 0; p < 8; ++p) {
        const float u0 = xs.f[3 * p + 0] * Nl;
        const float u1 = xs.f[3 * p + 1] * Nl;
        const float u2 = xs.f[3 * p + 2] * Nl;
        const float fl0 = floorf(u0), fl1 = floorf(u1), fl2 = floorf(u2);
        const float df0 = u0 - fl0, df1 = u1 - fl1, df2 = u2 - fl2;
        const uint32_t q0 = ((uint32_t)(int32_t)fl0) << 2;
        const uint32_t q1 = ((uint32_t)(int32_t)fl1) * P1_4;
        const uint32_t q2 = ((uint32_t)(int32_t)fl2) * P2_4;
        const uint32_t d0 = (q0 ^ (q0 + 4u))   & M4;
        const uint32_t d1 = (q1 ^ (q1 + P1_4)) & M4;
        const uint32_t d2 = (q2 ^ (q2 + P2_4)) & M4;
        uint32_t off = (q0 ^ q1 ^ q2) & M4;
        constexpr int gray[8] = {0, 1, 3, 2, 6, 7, 5, 4};
        h2 f[8];
#pragma unroll
        for (int j = 0; j < 8; ++j) {
            f[gray[j]] = *reinterpret_cast<const h2*>(tb + off);
            if (j < 7) {
                const int tog = gray[j] ^ gray[j + 1];
                off ^= (tog == 4) ? d0 : (tog == 2) ? d1 : d2;
            }
        }
        const _Float16 h0 = (_Float16)df0, h1 = (_Float16)df1, hz = (_Float16)df2;
        const h2 t0 = {h0, h0}, t1 = {h1, h1}, t2 = {hz, hz};
        h2 e0 = lerp2(f[0], f[1], t2);
        h2 e1 = lerp2(f[2], f[3], t2);
        h2 e2 = lerp2(f[4], f[5], t2);
        h2 e3 = lerp2(f[6], f[7], t2);
        h2 g0 = lerp2(e0, e1, t1);
        h2 g1 = lerp2(e2, e3, t1);
        h2 r  = lerp2(g0, g1, t0);
        out[(size_t)(n0 + p) * L_LEVELS + l] =
            make_float2((float)r.x, (float)r.y);
    }
}

extern "C" void kernel_launch(void* const* d_in, const int* in_sizes, int n_in,
                              void* d_out, int out_size, void* d_ws, size_t ws_size,
                              hipStream_t stream) {
    const float* x   = (const float*)d_in[0];
    const float* emb = (const float*)d_in[1];

    // ws layout: [0, 16 MiB) h2 ws array; [16 MiB, 17 MiB) fp16 emb copy.
    const size_t ws_arr_bytes = (size_t)N_PTS * L_LEVELS * sizeof(h2); // 16 MiB
    const size_t emb16_bytes  = (size_t)L_LEVELS * T_SIZE * sizeof(h2); // 1 MiB

    if (ws_size >= ws_arr_bytes + emb16_bytes) {
        h2* ws    = (h2*)d_ws;
        h2* emb16 = (h2*)((char*)d_ws + ws_arr_bytes);

        cvt_emb<<<512, 256, 0, stream>>>(
            (const float4*)emb, (h4*)emb16);
        hash_encode_pair<<<256, 1024, 0, stream>>>(x, emb16, ws);
        transpose_lnf_nlf<<<N_PTS / 512, 256, 0, stream>>>(
            ws, (float4*)d_out);
    } else {
        hash_encode_direct<<<1024, 512, 0, stream>>>(x, emb, (float2*)d_out);
    }
}